// Round 5
// baseline (3198.628 us; speedup 1.0000x reference)
//
#include <hip/hip_runtime.h>
#include <math.h>

#define BB 16
#define CC 128
#define LL 16000
#define KK 256
#define SS 3937
#define MM 4000
#define THRS 0.5f
#define STEP 0.1f   // float32(0.01/0.1) == 0.1f

// ---------------------------------------------------------------------------
// Strided conv1d (K=256, stride=4), fp32 register-tiled implicit GEMM.
// R14 VERBATIM (proven ~60us). Single fmaf chain per output, k ascending.
// [bit-path frozen] tx=s (coalesced epilogue), ty=c, W natural rows in LDS
// stride 68, double-buffered. x window in LDS.
// MODE 0: init. MODE 1: LCA update. MODE 2: final -> hardshrink to d_out.
// ---------------------------------------------------------------------------
template<int MODE>
__global__ __launch_bounds__(256, 2) void k_conv(
    const float* __restrict__ in0,     // x (MODE 0) or recon (MODE 1/2)
    const float* __restrict__ W,       // [C][K] natural
    float* __restrict__ drive,
    float* __restrict__ u)
{
    __shared__ __align__(16) float sW[2][128 * 68];  // 2 x 34.8 KB
    __shared__ __align__(16) float sX[768];
    __shared__ int sFlag;

    const int tid = threadIdx.x;
    const int tx = tid & 15;          // s-minor
    const int ty = tid >> 4;          // c-minor
    const int s0 = blockIdx.x * 128;
    const int b  = blockIdx.y;

    const int sc = tid >> 1;
    const int sg = (tid & 1) * 8;
    const float4* W4 = (const float4*)W;

    if (tid == 0) sFlag = 0;
    __syncthreads();

    bool nz = false;
    #pragma unroll
    for (int h = 0; h < 3; ++h) {
        int t = tid + 256 * h;
        int l = 4 * s0 + t;
        float v = (l < LL) ? in0[b * LL + l] : 0.f;
        sX[t] = v;
        nz |= (v != 0.f);
    }
    if (MODE != 0) { if (nz) atomicOr(&sFlag, 1); }
    __syncthreads();

    float acc[8][8];
    #pragma unroll
    for (int i = 0; i < 8; ++i)
        #pragma unroll
        for (int j = 0; j < 8; ++j) acc[i][j] = 0.f;

    const bool doit = (MODE == 0) || (sFlag != 0);   // block-uniform

    if (doit) {
        {
            float4* dst = (float4*)sW[0];
            #pragma unroll
            for (int w = 0; w < 8; ++w)
                dst[sc * 17 + sg + w] = W4[sc * 64 + sg + w];
        }
        __syncthreads();

        for (int kc = 0; kc < 4; ++kc) {         // k chunks ascending
            float4 pre[8];
            if (kc < 3) {
                #pragma unroll
                for (int w = 0; w < 8; ++w)
                    pre[w] = W4[sc * 64 + (kc + 1) * 16 + sg + w];
            }

            const float* wbuf = sW[kc & 1];
            const int xoff = 64 * kc;

            for (int kk4 = 0; kk4 < 16; ++kk4) {          // k ascending
                float4 xq[8];
                #pragma unroll
                for (int j = 0; j < 8; ++j)
                    xq[j] = *(const float4*)&sX[4 * (tx + 16 * j) + xoff + 4 * kk4];
                float4 w4[8];
                #pragma unroll
                for (int i = 0; i < 8; ++i)
                    w4[i] = *(const float4*)&wbuf[(ty + 16 * i) * 68 + 4 * kk4];
                #pragma unroll
                for (int dk = 0; dk < 4; ++dk) {
                    #pragma unroll
                    for (int i = 0; i < 8; ++i) {
                        float wv = (&w4[i].x)[dk];
                        #pragma unroll
                        for (int j = 0; j < 8; ++j)
                            acc[i][j] = fmaf(wv, (&xq[j].x)[dk], acc[i][j]);
                    }
                }
            }

            if (kc < 3) {
                float4* dst = (float4*)sW[(kc + 1) & 1];
                #pragma unroll
                for (int w = 0; w < 8; ++w)
                    dst[sc * 17 + sg + w] = pre[w];
            }
            __syncthreads();
        }
    }

    // epilogue: locked fp32 elementwise chain; s-contiguous stores
    #pragma unroll
    for (int j = 0; j < 8; ++j) {
        int s = s0 + tx + 16 * j;
        if (s < SS) {
            #pragma unroll
            for (int i = 0; i < 8; ++i) {
                int c = ty + 16 * i;
                size_t idx = (size_t)(b * CC + c) * SS + s;
                if (MODE == 0) {
                    float d = acc[i][j];
                    drive[idx] = d;
                    u[idx] = __fmul_rn(STEP, d);   // u1 = 0 + 0.1f*drive
                } else {
                    float uo = u[idx];
                    float dr = drive[idx];
                    float a  = (fabsf(uo) > THRS) ? uo : 0.f;
                    float t1 = __fsub_rn(dr, uo);
                    float t2 = __fsub_rn(t1, acc[i][j]);
                    float t3 = __fadd_rn(t2, a);
                    float t4 = __fmul_rn(STEP, t3);
                    float un = __fadd_rn(uo, t4);
                    if (MODE == 1) u[idx] = un;
                    else           u[idx] = (fabsf(un) > THRS) ? un : 0.f;  // final
                }
            }
        }
    }
}

// ---------------------------------------------------------------------------
// Transpose-conv (recon). Chain [bit-path frozen] identical to R5-R21:
//   recon[b][4m+r]: for c = 0..127 asc (4 stages x 32), q = 0..63 asc:
//       acc_r = fmaf(a[b][c][m-63+q], W[c][4*(63-q)+r], acc_r)
// R22: scalar-pipe weights, CLEAN form (post-mortems R18-R21: every prior
// attempt at uniform-w was poisoned by register blocks (av[64], pv[40]),
// sched_barrier pins, or per-q VALU readlanes with SGPR-write hazards).
//  - Inner loop is the NAIVE uniform code: wrow[k] with k compile-time,
//    wrow uniform (no tid) -> divergence analysis scalarizes ->
//    s_load_dwordx8/16 on the independent scalar pipe; v_fma_f32 reads
//    the SGPR operand directly. Zero VALU cost for w, zero LDS cost.
//  - Only remaining per-q ops: 1 ds_read (adjacent q merge to
//    ds_read2_b32) + 4 v_fmac. VALU/ch/wave = 512 cyc; LDS a-path
//    ~768 cyc/ch/CU -> expected wall ~41us + staging.
//  - No prefetch arrays, no sched_barriers, no readlanes. VGPR lean.
// ---------------------------------------------------------------------------
__global__ __launch_bounds__(256, 1) void k_recon(
    const float* __restrict__ u,
    const float* __restrict__ W,       // [C][K] natural layout
    float* __restrict__ recon)         // [B][LL]
{
    __shared__ __align__(16) float sA[32 * 320];   // 40.96 KB (stride 320)
    __shared__ int sFlag;

    const int tid = threadIdx.x;      // = m_local in [0,256)
    const int m0 = blockIdx.x * 256;
    const int b  = blockIdx.y;
    const int m  = m0 + tid;

    if (tid == 0) sFlag = 0;
    __syncthreads();

    float acc0 = 0.f, acc1 = 0.f, acc2 = 0.f, acc3 = 0.f;

    for (int cs = 0; cs < 4; ++cs) {            // 32-channel stages, c ascending
        const int c0 = cs * 32;

        // ---- stage a-tile (hardshrink at write; nz flag) ----
        bool nz = false;
        #pragma unroll
        for (int h = 0; h < 40; ++h) {
            int idx = tid + 256 * h;
            int cl  = idx / 320;
            int col = idx - cl * 320;
            int mm  = m0 - 63 + col;
            float v = 0.f;
            if (col < 319 && mm >= 0 && mm < SS) {
                float uu = u[(size_t)(b * CC + c0 + cl) * SS + mm];
                v = (fabsf(uu) > THRS) ? uu : 0.f;
            }
            sA[idx] = v;
            nz |= (v != 0.f);
        }
        if (nz) atomicOr(&sFlag, 1);

        __syncthreads();                        // staging + flags complete
        const int f = sFlag;                    // block-uniform read
        __syncthreads();                        // all threads have read f
        if (tid == 0) sFlag = 0;                // reset (ordered by loop-end barrier)

        if (f) {
            const float* Wbase = W + (size_t)c0 * KK;
            for (int cl = 0; cl < 32; ++cl) {   // c ascending
                const float* arow = sA + cl * 320 + tid;  // arow[q] = a[c][m-63+q]
                const float* wrow = Wbase + cl * KK;      // uniform row pointer
                #pragma unroll
                for (int q = 0; q < 64; ++q) {  // j = 63-q descending
                    float a = arow[q];          // ds_read (pairs -> ds_read2_b32)
                    const int k = 4 * (63 - q); // compile-time constant
                    acc0 = fmaf(a, wrow[k + 0], acc0);   // uniform -> s_load/SGPR
                    acc1 = fmaf(a, wrow[k + 1], acc1);
                    acc2 = fmaf(a, wrow[k + 2], acc2);
                    acc3 = fmaf(a, wrow[k + 3], acc3);
                }
            }
        }
        __syncthreads();   // sA reads done + sFlag reset visible before next stage
    }

    if (m < MM) {
        float4* o = (float4*)(recon + (size_t)b * LL + 4 * m);
        *o = make_float4(acc0, acc1, acc2, acc3);
    }
}

extern "C" void kernel_launch(void* const* d_in, const int* in_sizes, int n_in,
                              void* d_out, int out_size, void* d_ws, size_t ws_size,
                              hipStream_t stream) {
    const float* x = (const float*)d_in[0];   // [16][1][16000]
    const float* W = (const float*)d_in[1];   // [128][1][256]
    float* u = (float*)d_out;                 // u lives in d_out (fp32)

    float* ws    = (float*)d_ws;              // ~33.3 MB used
    float* drive = ws;                                    // 8062976
    float* recon = drive + (size_t)BB * CC * SS;          // 256000

    dim3 gConv(31, 16);   // ceil(3937/128) x B
    k_conv<0><<<gConv, 256, 0, stream>>>(x, W, drive, u);   // drive + u1

    for (int it = 0; it < 9; ++it) {   // iterations 2..10
        k_recon<<<dim3(16, 16), 256, 0, stream>>>(u, W, recon);
        if (it < 8)
            k_conv<1><<<gConv, 256, 0, stream>>>(recon, W, drive, u);
        else
            k_conv<2><<<gConv, 256, 0, stream>>>(recon, W, drive, u);  // final -> d_out
    }
}

// Round 6
// 2601.458 us; speedup vs baseline: 1.2296x; 1.2296x over previous
//
#include <hip/hip_runtime.h>
#include <math.h>

#define BB 16
#define CC 128
#define LL 16000
#define KK 256
#define SS 3937
#define MM 4000
#define THRS 0.5f
#define STEP 0.1f   // float32(0.01/0.1) == 0.1f

// ---------------------------------------------------------------------------
// Strided conv1d (K=256, stride=4), fp32 register-tiled implicit GEMM.
// R14 VERBATIM (proven ~60us). Single fmaf chain per output, k ascending.
// [bit-path frozen] tx=s (coalesced epilogue), ty=c, W natural rows in LDS
// stride 68, double-buffered. x window in LDS.
// MODE 0: init. MODE 1: LCA update. MODE 2: final -> hardshrink to d_out.
// ---------------------------------------------------------------------------
template<int MODE>
__global__ __launch_bounds__(256, 2) void k_conv(
    const float* __restrict__ in0,     // x (MODE 0) or recon (MODE 1/2)
    const float* __restrict__ W,       // [C][K] natural
    float* __restrict__ drive,
    float* __restrict__ u)
{
    __shared__ __align__(16) float sW[2][128 * 68];  // 2 x 34.8 KB
    __shared__ __align__(16) float sX[768];
    __shared__ int sFlag;

    const int tid = threadIdx.x;
    const int tx = tid & 15;          // s-minor
    const int ty = tid >> 4;          // c-minor
    const int s0 = blockIdx.x * 128;
    const int b  = blockIdx.y;

    const int sc = tid >> 1;
    const int sg = (tid & 1) * 8;
    const float4* W4 = (const float4*)W;

    if (tid == 0) sFlag = 0;
    __syncthreads();

    bool nz = false;
    #pragma unroll
    for (int h = 0; h < 3; ++h) {
        int t = tid + 256 * h;
        int l = 4 * s0 + t;
        float v = (l < LL) ? in0[b * LL + l] : 0.f;
        sX[t] = v;
        nz |= (v != 0.f);
    }
    if (MODE != 0) { if (nz) atomicOr(&sFlag, 1); }
    __syncthreads();

    float acc[8][8];
    #pragma unroll
    for (int i = 0; i < 8; ++i)
        #pragma unroll
        for (int j = 0; j < 8; ++j) acc[i][j] = 0.f;

    const bool doit = (MODE == 0) || (sFlag != 0);   // block-uniform

    if (doit) {
        {
            float4* dst = (float4*)sW[0];
            #pragma unroll
            for (int w = 0; w < 8; ++w)
                dst[sc * 17 + sg + w] = W4[sc * 64 + sg + w];
        }
        __syncthreads();

        for (int kc = 0; kc < 4; ++kc) {         // k chunks ascending
            float4 pre[8];
            if (kc < 3) {
                #pragma unroll
                for (int w = 0; w < 8; ++w)
                    pre[w] = W4[sc * 64 + (kc + 1) * 16 + sg + w];
            }

            const float* wbuf = sW[kc & 1];
            const int xoff = 64 * kc;

            for (int kk4 = 0; kk4 < 16; ++kk4) {          // k ascending
                float4 xq[8];
                #pragma unroll
                for (int j = 0; j < 8; ++j)
                    xq[j] = *(const float4*)&sX[4 * (tx + 16 * j) + xoff + 4 * kk4];
                float4 w4[8];
                #pragma unroll
                for (int i = 0; i < 8; ++i)
                    w4[i] = *(const float4*)&wbuf[(ty + 16 * i) * 68 + 4 * kk4];
                #pragma unroll
                for (int dk = 0; dk < 4; ++dk) {
                    #pragma unroll
                    for (int i = 0; i < 8; ++i) {
                        float wv = (&w4[i].x)[dk];
                        #pragma unroll
                        for (int j = 0; j < 8; ++j)
                            acc[i][j] = fmaf(wv, (&xq[j].x)[dk], acc[i][j]);
                    }
                }
            }

            if (kc < 3) {
                float4* dst = (float4*)sW[(kc + 1) & 1];
                #pragma unroll
                for (int w = 0; w < 8; ++w)
                    dst[sc * 17 + sg + w] = pre[w];
            }
            __syncthreads();
        }
    }

    // epilogue: locked fp32 elementwise chain; s-contiguous stores
    #pragma unroll
    for (int j = 0; j < 8; ++j) {
        int s = s0 + tx + 16 * j;
        if (s < SS) {
            #pragma unroll
            for (int i = 0; i < 8; ++i) {
                int c = ty + 16 * i;
                size_t idx = (size_t)(b * CC + c) * SS + s;
                if (MODE == 0) {
                    float d = acc[i][j];
                    drive[idx] = d;
                    u[idx] = __fmul_rn(STEP, d);   // u1 = 0 + 0.1f*drive
                } else {
                    float uo = u[idx];
                    float dr = drive[idx];
                    float a  = (fabsf(uo) > THRS) ? uo : 0.f;
                    float t1 = __fsub_rn(dr, uo);
                    float t2 = __fsub_rn(t1, acc[i][j]);
                    float t3 = __fadd_rn(t2, a);
                    float t4 = __fmul_rn(STEP, t3);
                    float un = __fadd_rn(uo, t4);
                    if (MODE == 1) u[idx] = un;
                    else           u[idx] = (fabsf(un) > THRS) ? un : 0.f;  // final
                }
            }
        }
    }
}

// ---------------------------------------------------------------------------
// Transpose-conv (recon). Chain [bit-path frozen] identical to R5-R22:
//   recon[b][4m+r]: for c = 0..127 asc (4 stages x 32), q = 0..63 asc:
//       acc_r = fmaf(a[b][c][m-63+q], W[c][4*(63-q)+r], acc_r)
// R23: DPP row_newbcast weight broadcast.
// Post-mortems R20-R22: occupancy is hard-capped at 1 wave/SIMD (64000
// threads / 1024 SIMDs; chain is serial per output), so per-wave time is
// nearly the SUM of issue+stall components. All three w-distribution
// mechanisms tried so far add overhead on a shared resource:
//   LDS b128 broadcast (R20, 182us): 64 extra LDS-pipe ops/ch/wave x4 waves
//   v_readlane (R21, 183us): 256 extra VALU + VALU->SGPR->VALU hazards
//   s_load (R22, 292us): SMEM shares lgkmcnt with DS -> in-loop drains
// DPP is the one free broadcast: the operand rides INSIDE the fma
// (VGPR->VGPR lane swizzle, no SGPR, no LDS, no extra counter).
//  - Lane p (=tid&15) of each 16-lane row holds W4[c][63-p-16*qb]
//    (reversed), loaded as 4 global_load_dwordx4 per channel,
//    double-buffered one full channel ahead (vmcnt-decoupled, L1-hot).
//  - Per q=16qb+qi: acc_r = fmaf(row_newbcast<qi>(w.r), a, acc_r).
//    row_newbcast:N (0x150+N, gfx90a+) broadcasts lane N of each row.
//  - a: scalar LDS reads (adjacent q merge to ds_read2_b32, ~32/ch).
//  - Same values, same chain order, same staging/flags -> bitwise safe.
// ---------------------------------------------------------------------------
#define DPPB(x, QI) __int_as_float(__builtin_amdgcn_update_dpp( \
    __float_as_int(x), __float_as_int(x), 0x150 + (QI), 0xF, 0xF, false))

#define QSTEP(WV, QB, QI) { \
    float a_ = arow[16 * (QB) + (QI)]; \
    acc0 = fmaf(DPPB(WV.x, QI), a_, acc0); \
    acc1 = fmaf(DPPB(WV.y, QI), a_, acc1); \
    acc2 = fmaf(DPPB(WV.z, QI), a_, acc2); \
    acc3 = fmaf(DPPB(WV.w, QI), a_, acc3); }

#define QBLOCK(WV, QB) \
    QSTEP(WV, QB, 0)  QSTEP(WV, QB, 1)  QSTEP(WV, QB, 2)  QSTEP(WV, QB, 3)  \
    QSTEP(WV, QB, 4)  QSTEP(WV, QB, 5)  QSTEP(WV, QB, 6)  QSTEP(WV, QB, 7)  \
    QSTEP(WV, QB, 8)  QSTEP(WV, QB, 9)  QSTEP(WV, QB, 10) QSTEP(WV, QB, 11) \
    QSTEP(WV, QB, 12) QSTEP(WV, QB, 13) QSTEP(WV, QB, 14) QSTEP(WV, QB, 15)

__global__ __launch_bounds__(256, 1) void k_recon(
    const float* __restrict__ u,
    const float* __restrict__ W,       // [C][K] natural layout
    float* __restrict__ recon)         // [B][LL]
{
    __shared__ __align__(16) float sA[32 * 320];   // 40.96 KB (stride 320)
    __shared__ int sFlag;

    const int tid = threadIdx.x;      // = m_local in [0,256)
    const int m0 = blockIdx.x * 256;
    const int b  = blockIdx.y;
    const int m  = m0 + tid;
    const int iw = 63 - (tid & 15);   // reversed row position for w loads

    if (tid == 0) sFlag = 0;
    __syncthreads();

    float acc0 = 0.f, acc1 = 0.f, acc2 = 0.f, acc3 = 0.f;
    const float4* Wg4 = (const float4*)W;

    for (int cs = 0; cs < 4; ++cs) {            // 32-channel stages, c ascending
        const int c0 = cs * 32;

        // ---- stage a-tile (hardshrink at write; nz flag) ----
        bool nz = false;
        #pragma unroll
        for (int h = 0; h < 40; ++h) {
            int idx = tid + 256 * h;
            int cl  = idx / 320;
            int col = idx - cl * 320;
            int mm  = m0 - 63 + col;
            float v = 0.f;
            if (col < 319 && mm >= 0 && mm < SS) {
                float uu = u[(size_t)(b * CC + c0 + cl) * SS + mm];
                v = (fabsf(uu) > THRS) ? uu : 0.f;
            }
            sA[idx] = v;
            nz |= (v != 0.f);
        }
        if (nz) atomicOr(&sFlag, 1);

        __syncthreads();                        // staging + flags complete
        const int f = sFlag;                    // block-uniform read
        __syncthreads();                        // all threads have read f
        if (tid == 0) sFlag = 0;                // reset (ordered by loop-end barrier)

        if (f) {
            // prologue: w for cl=0 (per-lane reversed-row float4s)
            float4 wa0 = Wg4[(size_t)(c0 + 0) * 64 + iw];
            float4 wa1 = Wg4[(size_t)(c0 + 0) * 64 + iw - 16];
            float4 wa2 = Wg4[(size_t)(c0 + 0) * 64 + iw - 32];
            float4 wa3 = Wg4[(size_t)(c0 + 0) * 64 + iw - 48];

            for (int cl = 0; cl < 32; ++cl) {   // c ascending
                float4 wb0, wb1, wb2, wb3;
                if (cl < 31) {                  // prefetch next channel's w
                    wb0 = Wg4[(size_t)(c0 + cl + 1) * 64 + iw];
                    wb1 = Wg4[(size_t)(c0 + cl + 1) * 64 + iw - 16];
                    wb2 = Wg4[(size_t)(c0 + cl + 1) * 64 + iw - 32];
                    wb3 = Wg4[(size_t)(c0 + cl + 1) * 64 + iw - 48];
                }

                const float* arow = sA + cl * 320 + tid;  // arow[q] = a[c][m-63+q]
                // q ascending: qb outer 0..3, qi inner 0..15
                QBLOCK(wa0, 0)
                QBLOCK(wa1, 1)
                QBLOCK(wa2, 2)
                QBLOCK(wa3, 3)

                wa0 = wb0; wa1 = wb1; wa2 = wb2; wa3 = wb3;
            }
        }
        __syncthreads();   // sA reads done + sFlag reset visible before next stage
    }

    if (m < MM) {
        float4* o = (float4*)(recon + (size_t)b * LL + 4 * m);
        *o = make_float4(acc0, acc1, acc2, acc3);
    }
}

extern "C" void kernel_launch(void* const* d_in, const int* in_sizes, int n_in,
                              void* d_out, int out_size, void* d_ws, size_t ws_size,
                              hipStream_t stream) {
    const float* x = (const float*)d_in[0];   // [16][1][16000]
    const float* W = (const float*)d_in[1];   // [128][1][256]
    float* u = (float*)d_out;                 // u lives in d_out (fp32)

    float* ws    = (float*)d_ws;              // ~33.3 MB used
    float* drive = ws;                                    // 8062976
    float* recon = drive + (size_t)BB * CC * SS;          // 256000

    dim3 gConv(31, 16);   // ceil(3937/128) x B
    k_conv<0><<<gConv, 256, 0, stream>>>(x, W, drive, u);   // drive + u1

    for (int it = 0; it < 9; ++it) {   // iterations 2..10
        k_recon<<<dim3(16, 16), 256, 0, stream>>>(u, W, recon);
        if (it < 8)
            k_conv<1><<<gConv, 256, 0, stream>>>(recon, W, drive, u);
        else
            k_conv<2><<<gConv, 256, 0, stream>>>(recon, W, drive, u);  // final -> d_out
    }
}

// Round 7
// 2281.599 us; speedup vs baseline: 1.4019x; 1.1402x over previous
//
#include <hip/hip_runtime.h>
#include <math.h>

#define BB 16
#define CC 128
#define LL 16000
#define KK 256
#define SS 3937
#define MM 4000
#define THRS 0.5f
#define STEP 0.1f   // float32(0.01/0.1) == 0.1f

// ---------------------------------------------------------------------------
// Strided conv1d (K=256, stride=4), fp32 register-tiled implicit GEMM.
// R14 VERBATIM (proven ~60us). Single fmaf chain per output, k ascending.
// [bit-path frozen] tx=s (coalesced epilogue), ty=c, W natural rows in LDS
// stride 68, double-buffered. x window in LDS.
// MODE 0: init. MODE 1: LCA update. MODE 2: final -> hardshrink to d_out.
// ---------------------------------------------------------------------------
template<int MODE>
__global__ __launch_bounds__(256, 2) void k_conv(
    const float* __restrict__ in0,     // x (MODE 0) or recon (MODE 1/2)
    const float* __restrict__ W,       // [C][K] natural
    float* __restrict__ drive,
    float* __restrict__ u)
{
    __shared__ __align__(16) float sW[2][128 * 68];  // 2 x 34.8 KB
    __shared__ __align__(16) float sX[768];
    __shared__ int sFlag;

    const int tid = threadIdx.x;
    const int tx = tid & 15;          // s-minor
    const int ty = tid >> 4;          // c-minor
    const int s0 = blockIdx.x * 128;
    const int b  = blockIdx.y;

    const int sc = tid >> 1;
    const int sg = (tid & 1) * 8;
    const float4* W4 = (const float4*)W;

    if (tid == 0) sFlag = 0;
    __syncthreads();

    bool nz = false;
    #pragma unroll
    for (int h = 0; h < 3; ++h) {
        int t = tid + 256 * h;
        int l = 4 * s0 + t;
        float v = (l < LL) ? in0[b * LL + l] : 0.f;
        sX[t] = v;
        nz |= (v != 0.f);
    }
    if (MODE != 0) { if (nz) atomicOr(&sFlag, 1); }
    __syncthreads();

    float acc[8][8];
    #pragma unroll
    for (int i = 0; i < 8; ++i)
        #pragma unroll
        for (int j = 0; j < 8; ++j) acc[i][j] = 0.f;

    const bool doit = (MODE == 0) || (sFlag != 0);   // block-uniform

    if (doit) {
        {
            float4* dst = (float4*)sW[0];
            #pragma unroll
            for (int w = 0; w < 8; ++w)
                dst[sc * 17 + sg + w] = W4[sc * 64 + sg + w];
        }
        __syncthreads();

        for (int kc = 0; kc < 4; ++kc) {         // k chunks ascending
            float4 pre[8];
            if (kc < 3) {
                #pragma unroll
                for (int w = 0; w < 8; ++w)
                    pre[w] = W4[sc * 64 + (kc + 1) * 16 + sg + w];
            }

            const float* wbuf = sW[kc & 1];
            const int xoff = 64 * kc;

            for (int kk4 = 0; kk4 < 16; ++kk4) {          // k ascending
                float4 xq[8];
                #pragma unroll
                for (int j = 0; j < 8; ++j)
                    xq[j] = *(const float4*)&sX[4 * (tx + 16 * j) + xoff + 4 * kk4];
                float4 w4[8];
                #pragma unroll
                for (int i = 0; i < 8; ++i)
                    w4[i] = *(const float4*)&wbuf[(ty + 16 * i) * 68 + 4 * kk4];
                #pragma unroll
                for (int dk = 0; dk < 4; ++dk) {
                    #pragma unroll
                    for (int i = 0; i < 8; ++i) {
                        float wv = (&w4[i].x)[dk];
                        #pragma unroll
                        for (int j = 0; j < 8; ++j)
                            acc[i][j] = fmaf(wv, (&xq[j].x)[dk], acc[i][j]);
                    }
                }
            }

            if (kc < 3) {
                float4* dst = (float4*)sW[(kc + 1) & 1];
                #pragma unroll
                for (int w = 0; w < 8; ++w)
                    dst[sc * 17 + sg + w] = pre[w];
            }
            __syncthreads();
        }
    }

    // epilogue: locked fp32 elementwise chain; s-contiguous stores
    #pragma unroll
    for (int j = 0; j < 8; ++j) {
        int s = s0 + tx + 16 * j;
        if (s < SS) {
            #pragma unroll
            for (int i = 0; i < 8; ++i) {
                int c = ty + 16 * i;
                size_t idx = (size_t)(b * CC + c) * SS + s;
                if (MODE == 0) {
                    float d = acc[i][j];
                    drive[idx] = d;
                    u[idx] = __fmul_rn(STEP, d);   // u1 = 0 + 0.1f*drive
                } else {
                    float uo = u[idx];
                    float dr = drive[idx];
                    float a  = (fabsf(uo) > THRS) ? uo : 0.f;
                    float t1 = __fsub_rn(dr, uo);
                    float t2 = __fsub_rn(t1, acc[i][j]);
                    float t3 = __fadd_rn(t2, a);
                    float t4 = __fmul_rn(STEP, t3);
                    float un = __fadd_rn(uo, t4);
                    if (MODE == 1) u[idx] = un;
                    else           u[idx] = (fabsf(un) > THRS) ? un : 0.f;  // final
                }
            }
        }
    }
}

// ---------------------------------------------------------------------------
// float readlane via int builtin (lane is compile-time constant here)
// ---------------------------------------------------------------------------
__device__ __forceinline__ float rdlane_f(float v, int lane) {
    union { float f; int i; } x;
    x.f = v;
    x.i = __builtin_amdgcn_readlane(x.i, lane);
    return x.f;
}

// ---------------------------------------------------------------------------
// Transpose-conv (recon). Chain [bit-path frozen] identical to R5-R23:
//   recon[b][4m+r]: for c = 0..127 asc (4 stages x 32), q = 0..63 asc:
//       acc_r = fmaf(a[b][c][m-63+q], W[c][4*(63-q)+r], acc_r)
// R24 = R21 (readlane-w, best 183us) + 4-buffer software-pipelined a-reads.
// Post-mortem model (consistent w/ R20-R23): 1 wave/SIMD -> time is the
// SUM of VALU issue (85us) + exposed a-read latency (98us) + staging.
// The flat unrolled q-loop pipelined ds_reads only ~1 q-group deep ->
// ~16 x 120cyc exposed waits per channel. Fix: blocks of 8 q's with a
// 4-buffer rotation loading block qb+2 while computing qb: gap = 2
// bodies (~128cyc) >= 120cyc ds latency -> exposure ~0. 8 blocks % 4
// == 0 -> rotation is channel-invariant, and qb=6/7 load the NEXT
// channel's blocks 0/1 (cross-channel boundary pipelined too).
// All buffer indices static under full unroll; 32 VGPRs of buffers.
// Chain values/order identical -> bitwise safe.
// ---------------------------------------------------------------------------
#define QB_STEP(QB, CUR, NXT2) { \
    const int b2_ = (QB) + 2; \
    const float* s_ = (b2_ < 8) ? (arow + 8 * b2_) : (arowN + 8 * (b2_ - 8)); \
    _Pragma("unroll") \
    for (int t = 0; t < 8; ++t) NXT2[t] = s_[t]; \
    _Pragma("unroll") \
    for (int qi = 0; qi < 8; ++qi) { \
        const int q = 8 * (QB) + qi; \
        float a_ = CUR[qi]; \
        acc0 = fmaf(a_, rdlane_f(wcur.x, 63 - q), acc0); \
        acc1 = fmaf(a_, rdlane_f(wcur.y, 63 - q), acc1); \
        acc2 = fmaf(a_, rdlane_f(wcur.z, 63 - q), acc2); \
        acc3 = fmaf(a_, rdlane_f(wcur.w, 63 - q), acc3); \
    } }

__global__ __launch_bounds__(256, 1) void k_recon(
    const float* __restrict__ u,
    const float* __restrict__ W,       // [C][K] natural layout
    float* __restrict__ recon)         // [B][LL]
{
    __shared__ __align__(16) float sA[32 * 320];   // 40.96 KB (stride 320)
    __shared__ int sFlag;

    const int tid  = threadIdx.x;      // = m_local in [0,256)
    const int lane = tid & 63;
    const int m0 = blockIdx.x * 256;
    const int b  = blockIdx.y;
    const int m  = m0 + tid;

    if (tid == 0) sFlag = 0;
    __syncthreads();

    float acc0 = 0.f, acc1 = 0.f, acc2 = 0.f, acc3 = 0.f;

    for (int cs = 0; cs < 4; ++cs) {            // 32-channel stages, c ascending
        const int c0 = cs * 32;

        // ---- stage a-tile (hardshrink at write; nz flag) ----
        bool nz = false;
        #pragma unroll
        for (int h = 0; h < 40; ++h) {
            int idx = tid + 256 * h;
            int cl  = idx / 320;
            int col = idx - cl * 320;
            int mm  = m0 - 63 + col;
            float v = 0.f;
            if (col < 319 && mm >= 0 && mm < SS) {
                float uu = u[(size_t)(b * CC + c0 + cl) * SS + mm];
                v = (fabsf(uu) > THRS) ? uu : 0.f;
            }
            sA[idx] = v;
            nz |= (v != 0.f);
        }
        if (nz) atomicOr(&sFlag, 1);

        __syncthreads();                        // staging + flags complete
        const int f = sFlag;                    // block-uniform read
        __syncthreads();                        // all threads have read f
        if (tid == 0) sFlag = 0;                // reset (ordered by loop-end barrier)

        if (f) {
            const float4* Wg4 = (const float4*)W;
            float4 wcur = Wg4[(size_t)c0 * 64 + lane];   // cl=0 row, cooperative

            // pipeline prologue: blocks 0,1 of channel 0
            float b_0[8], b_1[8], b_2[8], b_3[8];
            {
                const float* ar0 = sA + tid;
                #pragma unroll
                for (int t = 0; t < 8; ++t) b_0[t] = ar0[t];
                #pragma unroll
                for (int t = 0; t < 8; ++t) b_1[t] = ar0[8 + t];
            }

            for (int cl = 0; cl < 32; ++cl) {   // c ascending
                float4 wnxt = wcur;
                if (cl < 31) wnxt = Wg4[(size_t)(c0 + cl + 1) * 64 + lane];

                const float* arow  = sA + cl * 320 + tid;
                const float* arowN = (cl < 31) ? (sA + (cl + 1) * 320 + tid) : arow;

                QB_STEP(0, b_0, b_2)
                QB_STEP(1, b_1, b_3)
                QB_STEP(2, b_2, b_0)
                QB_STEP(3, b_3, b_1)
                QB_STEP(4, b_0, b_2)
                QB_STEP(5, b_1, b_3)
                QB_STEP(6, b_2, b_0)   // loads next channel's block 0
                QB_STEP(7, b_3, b_1)   // loads next channel's block 1

                wcur = wnxt;
            }
        }
        __syncthreads();   // sA reads done + sFlag reset visible before next stage
    }

    if (m < MM) {
        float4* o = (float4*)(recon + (size_t)b * LL + 4 * m);
        *o = make_float4(acc0, acc1, acc2, acc3);
    }
}

extern "C" void kernel_launch(void* const* d_in, const int* in_sizes, int n_in,
                              void* d_out, int out_size, void* d_ws, size_t ws_size,
                              hipStream_t stream) {
    const float* x = (const float*)d_in[0];   // [16][1][16000]
    const float* W = (const float*)d_in[1];   // [128][1][256]
    float* u = (float*)d_out;                 // u lives in d_out (fp32)

    float* ws    = (float*)d_ws;              // ~33.3 MB used
    float* drive = ws;                                    // 8062976
    float* recon = drive + (size_t)BB * CC * SS;          // 256000

    dim3 gConv(31, 16);   // ceil(3937/128) x B
    k_conv<0><<<gConv, 256, 0, stream>>>(x, W, drive, u);   // drive + u1

    for (int it = 0; it < 9; ++it) {   // iterations 2..10
        k_recon<<<dim3(16, 16), 256, 0, stream>>>(u, W, recon);
        if (it < 8)
            k_conv<1><<<gConv, 256, 0, stream>>>(recon, W, drive, u);
        else
            k_conv<2><<<gConv, 256, 0, stream>>>(recon, W, drive, u);  // final -> d_out
    }
}

// Round 8
// 2243.901 us; speedup vs baseline: 1.4255x; 1.0168x over previous
//
#include <hip/hip_runtime.h>
#include <math.h>

#define BB 16
#define CC 128
#define LL 16000
#define KK 256
#define SS 3937
#define MM 4000
#define THRS 0.5f
#define STEP 0.1f   // float32(0.01/0.1) == 0.1f

// ---------------------------------------------------------------------------
// Strided conv1d (K=256, stride=4), fp32 register-tiled implicit GEMM.
// R14 VERBATIM (proven ~60us). Single fmaf chain per output, k ascending.
// [bit-path frozen] tx=s (coalesced epilogue), ty=c, W natural rows in LDS
// stride 68, double-buffered. x window in LDS.
// MODE 0: init. MODE 1: LCA update. MODE 2: final -> hardshrink to d_out.
// ---------------------------------------------------------------------------
template<int MODE>
__global__ __launch_bounds__(256, 2) void k_conv(
    const float* __restrict__ in0,     // x (MODE 0) or recon (MODE 1/2)
    const float* __restrict__ W,       // [C][K] natural
    float* __restrict__ drive,
    float* __restrict__ u)
{
    __shared__ __align__(16) float sW[2][128 * 68];  // 2 x 34.8 KB
    __shared__ __align__(16) float sX[768];
    __shared__ int sFlag;

    const int tid = threadIdx.x;
    const int tx = tid & 15;          // s-minor
    const int ty = tid >> 4;          // c-minor
    const int s0 = blockIdx.x * 128;
    const int b  = blockIdx.y;

    const int sc = tid >> 1;
    const int sg = (tid & 1) * 8;
    const float4* W4 = (const float4*)W;

    if (tid == 0) sFlag = 0;
    __syncthreads();

    bool nz = false;
    #pragma unroll
    for (int h = 0; h < 3; ++h) {
        int t = tid + 256 * h;
        int l = 4 * s0 + t;
        float v = (l < LL) ? in0[b * LL + l] : 0.f;
        sX[t] = v;
        nz |= (v != 0.f);
    }
    if (MODE != 0) { if (nz) atomicOr(&sFlag, 1); }
    __syncthreads();

    float acc[8][8];
    #pragma unroll
    for (int i = 0; i < 8; ++i)
        #pragma unroll
        for (int j = 0; j < 8; ++j) acc[i][j] = 0.f;

    const bool doit = (MODE == 0) || (sFlag != 0);   // block-uniform

    if (doit) {
        {
            float4* dst = (float4*)sW[0];
            #pragma unroll
            for (int w = 0; w < 8; ++w)
                dst[sc * 17 + sg + w] = W4[sc * 64 + sg + w];
        }
        __syncthreads();

        for (int kc = 0; kc < 4; ++kc) {         // k chunks ascending
            float4 pre[8];
            if (kc < 3) {
                #pragma unroll
                for (int w = 0; w < 8; ++w)
                    pre[w] = W4[sc * 64 + (kc + 1) * 16 + sg + w];
            }

            const float* wbuf = sW[kc & 1];
            const int xoff = 64 * kc;

            for (int kk4 = 0; kk4 < 16; ++kk4) {          // k ascending
                float4 xq[8];
                #pragma unroll
                for (int j = 0; j < 8; ++j)
                    xq[j] = *(const float4*)&sX[4 * (tx + 16 * j) + xoff + 4 * kk4];
                float4 w4[8];
                #pragma unroll
                for (int i = 0; i < 8; ++i)
                    w4[i] = *(const float4*)&wbuf[(ty + 16 * i) * 68 + 4 * kk4];
                #pragma unroll
                for (int dk = 0; dk < 4; ++dk) {
                    #pragma unroll
                    for (int i = 0; i < 8; ++i) {
                        float wv = (&w4[i].x)[dk];
                        #pragma unroll
                        for (int j = 0; j < 8; ++j)
                            acc[i][j] = fmaf(wv, (&xq[j].x)[dk], acc[i][j]);
                    }
                }
            }

            if (kc < 3) {
                float4* dst = (float4*)sW[(kc + 1) & 1];
                #pragma unroll
                for (int w = 0; w < 8; ++w)
                    dst[sc * 17 + sg + w] = pre[w];
            }
            __syncthreads();
        }
    }

    // epilogue: locked fp32 elementwise chain; s-contiguous stores
    #pragma unroll
    for (int j = 0; j < 8; ++j) {
        int s = s0 + tx + 16 * j;
        if (s < SS) {
            #pragma unroll
            for (int i = 0; i < 8; ++i) {
                int c = ty + 16 * i;
                size_t idx = (size_t)(b * CC + c) * SS + s;
                if (MODE == 0) {
                    float d = acc[i][j];
                    drive[idx] = d;
                    u[idx] = __fmul_rn(STEP, d);   // u1 = 0 + 0.1f*drive
                } else {
                    float uo = u[idx];
                    float dr = drive[idx];
                    float a  = (fabsf(uo) > THRS) ? uo : 0.f;
                    float t1 = __fsub_rn(dr, uo);
                    float t2 = __fsub_rn(t1, acc[i][j]);
                    float t3 = __fadd_rn(t2, a);
                    float t4 = __fmul_rn(STEP, t3);
                    float un = __fadd_rn(uo, t4);
                    if (MODE == 1) u[idx] = un;
                    else           u[idx] = (fabsf(un) > THRS) ? un : 0.f;  // final
                }
            }
        }
    }
}

// ---------------------------------------------------------------------------
// float readlane via int builtin (lane is compile-time constant here)
// ---------------------------------------------------------------------------
__device__ __forceinline__ float rdlane_f(float v, int lane) {
    union { float f; int i; } x;
    x.f = v;
    x.i = __builtin_amdgcn_readlane(x.i, lane);
    return x.f;
}

// ---------------------------------------------------------------------------
// Transpose-conv (recon). Chain [bit-path frozen] identical to R5-R24:
//   recon[b][4m+r]: for c = 0..127 asc (4 stages x 32), q = 0..63 asc:
//       acc_r = fmaf(a[b][c][m-63+q], W[c][4*(63-q)+r], acc_r)
// R25 = R24 + software-pipelined readlanes (one q ahead).
// Post-mortem R24: a-read pipelining gained only 5us; VALUBusy 49%
// (88us busy vs 55us theoretical issue) + ~90us stall. Remaining
// consistent explanation: v_readlane writes an SGPR consumed by the
// IMMEDIATELY following v_fma (macro nested rdlane inside fmaf) ->
// VALU->SGPR->VALU hazard wait-states (~4-6 cyc) on all 256 pairs/ch.
// Fix: per q, issue the 4 readlanes for q+1 (independent), then the 4
// fmas for q using the previous iteration's SGPRs -> readlane->use gap
// ~10+ cyc. Pipeline is continuous across channel boundaries (q=63
// prefetches lane 63 of wnxt, already in registers).
// Chain values/order identical -> bitwise safe.
// ---------------------------------------------------------------------------
#define QB_STEP(QB, CUR, NXT2) { \
    const int b2_ = (QB) + 2; \
    const float* s_ = (b2_ < 8) ? (arow + 8 * b2_) : (arowN + 8 * (b2_ - 8)); \
    _Pragma("unroll") \
    for (int t = 0; t < 8; ++t) NXT2[t] = s_[t]; \
    _Pragma("unroll") \
    for (int qi = 0; qi < 8; ++qi) { \
        const int q = 8 * (QB) + qi; \
        float nwx, nwy, nwz, nww; \
        if (q < 63) {                       /* prefetch w for q+1 */ \
            nwx = rdlane_f(wcur.x, 62 - q); \
            nwy = rdlane_f(wcur.y, 62 - q); \
            nwz = rdlane_f(wcur.z, 62 - q); \
            nww = rdlane_f(wcur.w, 62 - q); \
        } else {                            /* next channel's q=0 */ \
            nwx = rdlane_f(wnxt.x, 63); \
            nwy = rdlane_f(wnxt.y, 63); \
            nwz = rdlane_f(wnxt.z, 63); \
            nww = rdlane_f(wnxt.w, 63); \
        } \
        float a_ = CUR[qi]; \
        acc0 = fmaf(a_, wqx, acc0); \
        acc1 = fmaf(a_, wqy, acc1); \
        acc2 = fmaf(a_, wqz, acc2); \
        acc3 = fmaf(a_, wqw, acc3); \
        wqx = nwx; wqy = nwy; wqz = nwz; wqw = nww; \
    } }

__global__ __launch_bounds__(256, 1) void k_recon(
    const float* __restrict__ u,
    const float* __restrict__ W,       // [C][K] natural layout
    float* __restrict__ recon)         // [B][LL]
{
    __shared__ __align__(16) float sA[32 * 320];   // 40.96 KB (stride 320)
    __shared__ int sFlag;

    const int tid  = threadIdx.x;      // = m_local in [0,256)
    const int lane = tid & 63;
    const int m0 = blockIdx.x * 256;
    const int b  = blockIdx.y;
    const int m  = m0 + tid;

    if (tid == 0) sFlag = 0;
    __syncthreads();

    float acc0 = 0.f, acc1 = 0.f, acc2 = 0.f, acc3 = 0.f;

    for (int cs = 0; cs < 4; ++cs) {            // 32-channel stages, c ascending
        const int c0 = cs * 32;

        // ---- stage a-tile (hardshrink at write; nz flag) ----
        bool nz = false;
        #pragma unroll
        for (int h = 0; h < 40; ++h) {
            int idx = tid + 256 * h;
            int cl  = idx / 320;
            int col = idx - cl * 320;
            int mm  = m0 - 63 + col;
            float v = 0.f;
            if (col < 319 && mm >= 0 && mm < SS) {
                float uu = u[(size_t)(b * CC + c0 + cl) * SS + mm];
                v = (fabsf(uu) > THRS) ? uu : 0.f;
            }
            sA[idx] = v;
            nz |= (v != 0.f);
        }
        if (nz) atomicOr(&sFlag, 1);

        __syncthreads();                        // staging + flags complete
        const int f = sFlag;                    // block-uniform read
        __syncthreads();                        // all threads have read f
        if (tid == 0) sFlag = 0;                // reset (ordered by loop-end barrier)

        if (f) {
            const float4* Wg4 = (const float4*)W;
            float4 wcur = Wg4[(size_t)c0 * 64 + lane];   // cl=0 row, cooperative

            // a-pipeline prologue: blocks 0,1 of channel 0
            float b_0[8], b_1[8], b_2[8], b_3[8];
            {
                const float* ar0 = sA + tid;
                #pragma unroll
                for (int t = 0; t < 8; ++t) b_0[t] = ar0[t];
                #pragma unroll
                for (int t = 0; t < 8; ++t) b_1[t] = ar0[8 + t];
            }

            // w-pipeline prologue: q=0 of channel 0
            float wqx = rdlane_f(wcur.x, 63);
            float wqy = rdlane_f(wcur.y, 63);
            float wqz = rdlane_f(wcur.z, 63);
            float wqw = rdlane_f(wcur.w, 63);

            for (int cl = 0; cl < 32; ++cl) {   // c ascending
                float4 wnxt = wcur;
                if (cl < 31) wnxt = Wg4[(size_t)(c0 + cl + 1) * 64 + lane];

                const float* arow  = sA + cl * 320 + tid;
                const float* arowN = (cl < 31) ? (sA + (cl + 1) * 320 + tid) : arow;

                QB_STEP(0, b_0, b_2)
                QB_STEP(1, b_1, b_3)
                QB_STEP(2, b_2, b_0)
                QB_STEP(3, b_3, b_1)
                QB_STEP(4, b_0, b_2)
                QB_STEP(5, b_1, b_3)
                QB_STEP(6, b_2, b_0)   // loads next channel's block 0
                QB_STEP(7, b_3, b_1)   // loads next channel's block 1

                wcur = wnxt;
            }
        }
        __syncthreads();   // sA reads done + sFlag reset visible before next stage
    }

    if (m < MM) {
        float4* o = (float4*)(recon + (size_t)b * LL + 4 * m);
        *o = make_float4(acc0, acc1, acc2, acc3);
    }
}

extern "C" void kernel_launch(void* const* d_in, const int* in_sizes, int n_in,
                              void* d_out, int out_size, void* d_ws, size_t ws_size,
                              hipStream_t stream) {
    const float* x = (const float*)d_in[0];   // [16][1][16000]
    const float* W = (const float*)d_in[1];   // [128][1][256]
    float* u = (float*)d_out;                 // u lives in d_out (fp32)

    float* ws    = (float*)d_ws;              // ~33.3 MB used
    float* drive = ws;                                    // 8062976
    float* recon = drive + (size_t)BB * CC * SS;          // 256000

    dim3 gConv(31, 16);   // ceil(3937/128) x B
    k_conv<0><<<gConv, 256, 0, stream>>>(x, W, drive, u);   // drive + u1

    for (int it = 0; it < 9; ++it) {   // iterations 2..10
        k_recon<<<dim3(16, 16), 256, 0, stream>>>(u, W, recon);
        if (it < 8)
            k_conv<1><<<gConv, 256, 0, stream>>>(recon, W, drive, u);
        else
            k_conv<2><<<gConv, 256, 0, stream>>>(recon, W, drive, u);  // final -> d_out
    }
}

// Round 9
// 1965.399 us; speedup vs baseline: 1.6275x; 1.1417x over previous
//
#include <hip/hip_runtime.h>
#include <math.h>

#define BB 16
#define CC 128
#define LL 16000
#define KK 256
#define SS 3937
#define MM 4000
#define THRS 0.5f
#define STEP 0.1f   // float32(0.01/0.1) == 0.1f

// ---------------------------------------------------------------------------
// Strided conv1d (K=256, stride=4), fp32 register-tiled implicit GEMM.
// R14 VERBATIM (proven ~60us). Single fmaf chain per output, k ascending.
// [bit-path frozen] tx=s (coalesced epilogue), ty=c, W natural rows in LDS
// stride 68, double-buffered. x window in LDS.
// MODE 0: init. MODE 1: LCA update. MODE 2: final -> hardshrink to d_out.
// ---------------------------------------------------------------------------
template<int MODE>
__global__ __launch_bounds__(256, 2) void k_conv(
    const float* __restrict__ in0,     // x (MODE 0) or recon (MODE 1/2)
    const float* __restrict__ W,       // [C][K] natural
    float* __restrict__ drive,
    float* __restrict__ u)
{
    __shared__ __align__(16) float sW[2][128 * 68];  // 2 x 34.8 KB
    __shared__ __align__(16) float sX[768];
    __shared__ int sFlag;

    const int tid = threadIdx.x;
    const int tx = tid & 15;          // s-minor
    const int ty = tid >> 4;          // c-minor
    const int s0 = blockIdx.x * 128;
    const int b  = blockIdx.y;

    const int sc = tid >> 1;
    const int sg = (tid & 1) * 8;
    const float4* W4 = (const float4*)W;

    if (tid == 0) sFlag = 0;
    __syncthreads();

    bool nz = false;
    #pragma unroll
    for (int h = 0; h < 3; ++h) {
        int t = tid + 256 * h;
        int l = 4 * s0 + t;
        float v = (l < LL) ? in0[b * LL + l] : 0.f;
        sX[t] = v;
        nz |= (v != 0.f);
    }
    if (MODE != 0) { if (nz) atomicOr(&sFlag, 1); }
    __syncthreads();

    float acc[8][8];
    #pragma unroll
    for (int i = 0; i < 8; ++i)
        #pragma unroll
        for (int j = 0; j < 8; ++j) acc[i][j] = 0.f;

    const bool doit = (MODE == 0) || (sFlag != 0);   // block-uniform

    if (doit) {
        {
            float4* dst = (float4*)sW[0];
            #pragma unroll
            for (int w = 0; w < 8; ++w)
                dst[sc * 17 + sg + w] = W4[sc * 64 + sg + w];
        }
        __syncthreads();

        for (int kc = 0; kc < 4; ++kc) {         // k chunks ascending
            float4 pre[8];
            if (kc < 3) {
                #pragma unroll
                for (int w = 0; w < 8; ++w)
                    pre[w] = W4[sc * 64 + (kc + 1) * 16 + sg + w];
            }

            const float* wbuf = sW[kc & 1];
            const int xoff = 64 * kc;

            for (int kk4 = 0; kk4 < 16; ++kk4) {          // k ascending
                float4 xq[8];
                #pragma unroll
                for (int j = 0; j < 8; ++j)
                    xq[j] = *(const float4*)&sX[4 * (tx + 16 * j) + xoff + 4 * kk4];
                float4 w4[8];
                #pragma unroll
                for (int i = 0; i < 8; ++i)
                    w4[i] = *(const float4*)&wbuf[(ty + 16 * i) * 68 + 4 * kk4];
                #pragma unroll
                for (int dk = 0; dk < 4; ++dk) {
                    #pragma unroll
                    for (int i = 0; i < 8; ++i) {
                        float wv = (&w4[i].x)[dk];
                        #pragma unroll
                        for (int j = 0; j < 8; ++j)
                            acc[i][j] = fmaf(wv, (&xq[j].x)[dk], acc[i][j]);
                    }
                }
            }

            if (kc < 3) {
                float4* dst = (float4*)sW[(kc + 1) & 1];
                #pragma unroll
                for (int w = 0; w < 8; ++w)
                    dst[sc * 17 + sg + w] = pre[w];
            }
            __syncthreads();
        }
    }

    // epilogue: locked fp32 elementwise chain; s-contiguous stores
    #pragma unroll
    for (int j = 0; j < 8; ++j) {
        int s = s0 + tx + 16 * j;
        if (s < SS) {
            #pragma unroll
            for (int i = 0; i < 8; ++i) {
                int c = ty + 16 * i;
                size_t idx = (size_t)(b * CC + c) * SS + s;
                if (MODE == 0) {
                    float d = acc[i][j];
                    drive[idx] = d;
                    u[idx] = __fmul_rn(STEP, d);   // u1 = 0 + 0.1f*drive
                } else {
                    float uo = u[idx];
                    float dr = drive[idx];
                    float a  = (fabsf(uo) > THRS) ? uo : 0.f;
                    float t1 = __fsub_rn(dr, uo);
                    float t2 = __fsub_rn(t1, acc[i][j]);
                    float t3 = __fadd_rn(t2, a);
                    float t4 = __fmul_rn(STEP, t3);
                    float un = __fadd_rn(uo, t4);
                    if (MODE == 1) u[idx] = un;
                    else           u[idx] = (fabsf(un) > THRS) ? un : 0.f;  // final
                }
            }
        }
    }
}

// ---------------------------------------------------------------------------
// float readlane via int builtin (lane is compile-time constant here)
// ---------------------------------------------------------------------------
__device__ __forceinline__ float rdlane_f(float v, int lane) {
    union { float f; int i; } x;
    x.f = v;
    x.i = __builtin_amdgcn_readlane(x.i, lane);
    return x.f;
}

// ---------------------------------------------------------------------------
// Transpose-conv (recon). Chain [bit-path frozen] identical to R5-R25:
//   recon[b][4m+r]: for c = 0..127 asc (4 stages x 32), q = 0..63 asc:
//       acc_r = fmaf(a[b][c][m-63+q], W[c][4*(63-q)+r], acc_r)
// R26 = R21 structure + r-PAIR split for 2 waves/SIMD occupancy.
// Post-mortem R21/R24/R25: three different single-wave schedules all hit
// ~180us = ~3400 cyc/ch/CU vs ~1100 cyc/ch of instruction stream. The
// ~2300cyc/ch stall is invisible to intra-wave scheduling -> the machine
// needs TLP. Occupancy was capped at 1 wave/SIMD by 64000 threads.
//  - Block = 512 threads, grid (16,16) unchanged: threads 0-255 own
//    r={0,1}, 256-511 own r={2,3} of the same 256-m tile. 131072
//    threads = 2048 waves = 2 waves/SIMD; stalls now hide under the
//    co-resident wave. (R18's r-split failed for OTHER reasons: per-q
//    VMEM float2 w-loads + av-array, never isolated the split.)
//  - Per wave per ch: 64 a-reads (same LDS addrs, read2-merged) +
//    128 readlanes + 128 fmas. Same total VALU per SIMD, half per wave.
//  - sA staged once per block (41KB, 1 block/CU); flat q-loop as R21
//    (R24/R25 pipelining bought nothing -> keep it simple).
//  - Chain per output untouched (c asc, q asc, same operand values,
//    serial in one thread) -> bitwise safe.
// ---------------------------------------------------------------------------
__global__ __launch_bounds__(512, 1) void k_recon(
    const float* __restrict__ u,
    const float* __restrict__ W,       // [C][K] natural layout
    float* __restrict__ recon)         // [B][LL]
{
    __shared__ __align__(16) float sA[32 * 320];   // 40.96 KB (stride 320)
    __shared__ int sFlag;

    const int tid  = threadIdx.x;      // [0,512)
    const int lane = tid & 63;
    const int ml   = tid & 255;        // m_local
    const int rp   = (tid >> 8) << 1;  // 0 | 2, wave-uniform
    const int m0 = blockIdx.x * 256;
    const int b  = blockIdx.y;
    const int m  = m0 + ml;

    if (tid == 0) sFlag = 0;
    __syncthreads();

    float accA = 0.f, accB = 0.f;      // r = rp, rp+1

    for (int cs = 0; cs < 4; ++cs) {            // 32-channel stages, c ascending
        const int c0 = cs * 32;

        // ---- stage a-tile (hardshrink at write; nz flag) ----
        bool nz = false;
        #pragma unroll
        for (int h = 0; h < 20; ++h) {          // 20*512 = 32*320 elements
            int idx = tid + 512 * h;
            int cl  = idx / 320;
            int col = idx - cl * 320;
            int mm  = m0 - 63 + col;
            float v = 0.f;
            if (col < 319 && mm >= 0 && mm < SS) {
                float uu = u[(size_t)(b * CC + c0 + cl) * SS + mm];
                v = (fabsf(uu) > THRS) ? uu : 0.f;
            }
            sA[idx] = v;
            nz |= (v != 0.f);
        }
        if (nz) atomicOr(&sFlag, 1);

        __syncthreads();                        // staging + flags complete
        const int f = sFlag;                    // block-uniform read
        __syncthreads();                        // all threads have read f
        if (tid == 0) sFlag = 0;                // reset (ordered by loop-end barrier)

        if (f) {
            const float4* Wg4 = (const float4*)W;
            float4 wcur = Wg4[(size_t)c0 * 64 + lane];   // cl=0 row, cooperative

            for (int cl = 0; cl < 32; ++cl) {   // c ascending
                float4 wnxt = wcur;
                if (cl < 31) wnxt = Wg4[(size_t)(c0 + cl + 1) * 64 + lane];

                // this wave's two W components (rp uniform per wave)
                float wA = (rp == 0) ? wcur.x : wcur.z;
                float wB = (rp == 0) ? wcur.y : wcur.w;

                const float* arow = sA + cl * 320 + ml;   // arow[q] = a[c][m-63+q]
                #pragma unroll
                for (int q = 0; q < 64; ++q) {  // j = 63-q descending
                    float a_ = arow[q];         // ds_read (pairs -> ds_read2_b32)
                    accA = fmaf(a_, rdlane_f(wA, 63 - q), accA);
                    accB = fmaf(a_, rdlane_f(wB, 63 - q), accB);
                }
                wcur = wnxt;
            }
        }
        __syncthreads();   // sA reads done + sFlag reset visible before next stage
    }

    if (m < MM) {
        float2* o = (float2*)(recon + (size_t)b * LL + 4 * m + rp);
        *o = make_float2(accA, accB);
    }
}

extern "C" void kernel_launch(void* const* d_in, const int* in_sizes, int n_in,
                              void* d_out, int out_size, void* d_ws, size_t ws_size,
                              hipStream_t stream) {
    const float* x = (const float*)d_in[0];   // [16][1][16000]
    const float* W = (const float*)d_in[1];   // [128][1][256]
    float* u = (float*)d_out;                 // u lives in d_out (fp32)

    float* ws    = (float*)d_ws;              // ~33.3 MB used
    float* drive = ws;                                    // 8062976
    float* recon = drive + (size_t)BB * CC * SS;          // 256000

    dim3 gConv(31, 16);   // ceil(3937/128) x B
    k_conv<0><<<gConv, 256, 0, stream>>>(x, W, drive, u);   // drive + u1

    for (int it = 0; it < 9; ++it) {   // iterations 2..10
        k_recon<<<dim3(16, 16), 512, 0, stream>>>(u, W, recon);
        if (it < 8)
            k_conv<1><<<gConv, 256, 0, stream>>>(recon, W, drive, u);
        else
            k_conv<2><<<gConv, 256, 0, stream>>>(recon, W, drive, u);  // final -> d_out
    }
}

// Round 10
// 1816.562 us; speedup vs baseline: 1.7608x; 1.0819x over previous
//
#include <hip/hip_runtime.h>
#include <math.h>

#define BB 16
#define CC 128
#define LL 16000
#define KK 256
#define SS 3937
#define MM 4000
#define THRS 0.5f
#define STEP 0.1f   // float32(0.01/0.1) == 0.1f

// ---------------------------------------------------------------------------
// Strided conv1d (K=256, stride=4), fp32 register-tiled implicit GEMM.
// R14 VERBATIM (proven ~60us). Single fmaf chain per output, k ascending.
// [bit-path frozen] tx=s (coalesced epilogue), ty=c, W natural rows in LDS
// stride 68, double-buffered. x window in LDS.
// MODE 0: init. MODE 1: LCA update. MODE 2: final -> hardshrink to d_out.
// ---------------------------------------------------------------------------
template<int MODE>
__global__ __launch_bounds__(256, 2) void k_conv(
    const float* __restrict__ in0,     // x (MODE 0) or recon (MODE 1/2)
    const float* __restrict__ W,       // [C][K] natural
    float* __restrict__ drive,
    float* __restrict__ u)
{
    __shared__ __align__(16) float sW[2][128 * 68];  // 2 x 34.8 KB
    __shared__ __align__(16) float sX[768];
    __shared__ int sFlag;

    const int tid = threadIdx.x;
    const int tx = tid & 15;          // s-minor
    const int ty = tid >> 4;          // c-minor
    const int s0 = blockIdx.x * 128;
    const int b  = blockIdx.y;

    const int sc = tid >> 1;
    const int sg = (tid & 1) * 8;
    const float4* W4 = (const float4*)W;

    if (tid == 0) sFlag = 0;
    __syncthreads();

    bool nz = false;
    #pragma unroll
    for (int h = 0; h < 3; ++h) {
        int t = tid + 256 * h;
        int l = 4 * s0 + t;
        float v = (l < LL) ? in0[b * LL + l] : 0.f;
        sX[t] = v;
        nz |= (v != 0.f);
    }
    if (MODE != 0) { if (nz) atomicOr(&sFlag, 1); }
    __syncthreads();

    float acc[8][8];
    #pragma unroll
    for (int i = 0; i < 8; ++i)
        #pragma unroll
        for (int j = 0; j < 8; ++j) acc[i][j] = 0.f;

    const bool doit = (MODE == 0) || (sFlag != 0);   // block-uniform

    if (doit) {
        {
            float4* dst = (float4*)sW[0];
            #pragma unroll
            for (int w = 0; w < 8; ++w)
                dst[sc * 17 + sg + w] = W4[sc * 64 + sg + w];
        }
        __syncthreads();

        for (int kc = 0; kc < 4; ++kc) {         // k chunks ascending
            float4 pre[8];
            if (kc < 3) {
                #pragma unroll
                for (int w = 0; w < 8; ++w)
                    pre[w] = W4[sc * 64 + (kc + 1) * 16 + sg + w];
            }

            const float* wbuf = sW[kc & 1];
            const int xoff = 64 * kc;

            for (int kk4 = 0; kk4 < 16; ++kk4) {          // k ascending
                float4 xq[8];
                #pragma unroll
                for (int j = 0; j < 8; ++j)
                    xq[j] = *(const float4*)&sX[4 * (tx + 16 * j) + xoff + 4 * kk4];
                float4 w4[8];
                #pragma unroll
                for (int i = 0; i < 8; ++i)
                    w4[i] = *(const float4*)&wbuf[(ty + 16 * i) * 68 + 4 * kk4];
                #pragma unroll
                for (int dk = 0; dk < 4; ++dk) {
                    #pragma unroll
                    for (int i = 0; i < 8; ++i) {
                        float wv = (&w4[i].x)[dk];
                        #pragma unroll
                        for (int j = 0; j < 8; ++j)
                            acc[i][j] = fmaf(wv, (&xq[j].x)[dk], acc[i][j]);
                    }
                }
            }

            if (kc < 3) {
                float4* dst = (float4*)sW[(kc + 1) & 1];
                #pragma unroll
                for (int w = 0; w < 8; ++w)
                    dst[sc * 17 + sg + w] = pre[w];
            }
            __syncthreads();
        }
    }

    // epilogue: locked fp32 elementwise chain; s-contiguous stores
    #pragma unroll
    for (int j = 0; j < 8; ++j) {
        int s = s0 + tx + 16 * j;
        if (s < SS) {
            #pragma unroll
            for (int i = 0; i < 8; ++i) {
                int c = ty + 16 * i;
                size_t idx = (size_t)(b * CC + c) * SS + s;
                if (MODE == 0) {
                    float d = acc[i][j];
                    drive[idx] = d;
                    u[idx] = __fmul_rn(STEP, d);   // u1 = 0 + 0.1f*drive
                } else {
                    float uo = u[idx];
                    float dr = drive[idx];
                    float a  = (fabsf(uo) > THRS) ? uo : 0.f;
                    float t1 = __fsub_rn(dr, uo);
                    float t2 = __fsub_rn(t1, acc[i][j]);
                    float t3 = __fadd_rn(t2, a);
                    float t4 = __fmul_rn(STEP, t3);
                    float un = __fadd_rn(uo, t4);
                    if (MODE == 1) u[idx] = un;
                    else           u[idx] = (fabsf(un) > THRS) ? un : 0.f;  // final
                }
            }
        }
    }
}

// ---------------------------------------------------------------------------
// Transpose-conv (recon). Chain [bit-path frozen] identical to R5-R26:
//   recon[b][4m+r]: for c = 0..127 asc (4 stages x 32), q = 0..63 asc:
//       acc_r = fmaf(a[b][c][m-63+q], W[c][4*(63-q)+r], acc_r)
// R27 = R26 (r-pair split, 2 waves/SIMD, 145us) + fmac_dpp weight
// broadcast. Post-mortem R26: issue-rate-dominated; half the VALU is the
// readlane broadcast tax (128 rl + 128 fma per ch per wave).
//  - v_fmac_f32_dpp acc, w, a row_newbcast:qi -- the broadcast rides
//    inside the fma (VOP2+DPP, src0 swizzle). Zero extra ops. R23
//    PASSED with this layout+row_newbcast semantics (update_dpp builtin
//    was just unfused); now emitted directly as inline asm.
//  - W layout per wave (R23-proven): lane p=tid&15 holds, per quarter
//    qb, float2 W[c][4*(63-16qb-p)+rp .. +1] (reversed rows, replicated
//    across the 4 16-lane rows). 4 b64 loads/ch/wave, prefetched one
//    channel ahead (vmcnt-decoupled; w regs written by loads, not VALU
//    -> no VALU->DPP hazard).
//  - Per q: 1/2 ds_read2 + 2 fmac_dpp. VALU/ch/wave 512 -> ~280 cyc.
//  - Chain values/order identical -> bitwise safe.
// ---------------------------------------------------------------------------
#define FMAC_DPP(ACC, WREG, AREG, QI) \
    asm("v_fmac_f32_dpp %0, %1, %2 row_newbcast:" #QI " row_mask:0xf bank_mask:0xf" \
        : "+v"(ACC) : "v"(WREG), "v"(AREG))

#define QSTEP2(WQ, QB, QI) { \
    float a_ = arow[16 * (QB) + (QI)]; \
    FMAC_DPP(accA, WQ.x, a_, QI); \
    FMAC_DPP(accB, WQ.y, a_, QI); }

#define QBLOCK2(WQ, QB) \
    QSTEP2(WQ, QB, 0)  QSTEP2(WQ, QB, 1)  QSTEP2(WQ, QB, 2)  QSTEP2(WQ, QB, 3)  \
    QSTEP2(WQ, QB, 4)  QSTEP2(WQ, QB, 5)  QSTEP2(WQ, QB, 6)  QSTEP2(WQ, QB, 7)  \
    QSTEP2(WQ, QB, 8)  QSTEP2(WQ, QB, 9)  QSTEP2(WQ, QB, 10) QSTEP2(WQ, QB, 11) \
    QSTEP2(WQ, QB, 12) QSTEP2(WQ, QB, 13) QSTEP2(WQ, QB, 14) QSTEP2(WQ, QB, 15)

__global__ __launch_bounds__(512, 1) void k_recon(
    const float* __restrict__ u,
    const float* __restrict__ W,       // [C][K] natural layout
    float* __restrict__ recon)         // [B][LL]
{
    __shared__ __align__(16) float sA[32 * 320];   // 40.96 KB (stride 320)
    __shared__ int sFlag;

    const int tid  = threadIdx.x;      // [0,512)
    const int p    = tid & 15;         // row position for w layout
    const int ml   = tid & 255;        // m_local
    const int rp   = (tid >> 8) << 1;  // 0 | 2, wave-uniform
    const int m0 = blockIdx.x * 256;
    const int b  = blockIdx.y;
    const int m  = m0 + ml;

    if (tid == 0) sFlag = 0;
    __syncthreads();

    float accA = 0.f, accB = 0.f;      // r = rp, rp+1

    // per-lane w fetch bases: quarter qb, element 4*(63-16qb-p)+rp
    const float* Wq0 = W + 4 * (63 - p)      + rp;
    const float* Wq1 = W + 4 * (63 - 16 - p) + rp;
    const float* Wq2 = W + 4 * (63 - 32 - p) + rp;
    const float* Wq3 = W + 4 * (63 - 48 - p) + rp;

    for (int cs = 0; cs < 4; ++cs) {            // 32-channel stages, c ascending
        const int c0 = cs * 32;

        // ---- stage a-tile (hardshrink at write; nz flag) ----
        bool nz = false;
        #pragma unroll
        for (int h = 0; h < 20; ++h) {          // 20*512 = 32*320 elements
            int idx = tid + 512 * h;
            int cl  = idx / 320;
            int col = idx - cl * 320;
            int mm  = m0 - 63 + col;
            float v = 0.f;
            if (col < 319 && mm >= 0 && mm < SS) {
                float uu = u[(size_t)(b * CC + c0 + cl) * SS + mm];
                v = (fabsf(uu) > THRS) ? uu : 0.f;
            }
            sA[idx] = v;
            nz |= (v != 0.f);
        }
        if (nz) atomicOr(&sFlag, 1);

        __syncthreads();                        // staging + flags complete
        const int f = sFlag;                    // block-uniform read
        __syncthreads();                        // all threads have read f
        if (tid == 0) sFlag = 0;                // reset (ordered by loop-end barrier)

        if (f) {
            // prologue: w quarters for cl=0
            float2 w0 = *(const float2*)(Wq0 + (size_t)c0 * KK);
            float2 w1 = *(const float2*)(Wq1 + (size_t)c0 * KK);
            float2 w2 = *(const float2*)(Wq2 + (size_t)c0 * KK);
            float2 w3 = *(const float2*)(Wq3 + (size_t)c0 * KK);

            for (int cl = 0; cl < 32; ++cl) {   // c ascending
                float2 n0, n1, n2, n3;
                if (cl < 31) {                  // prefetch next channel
                    size_t co = (size_t)(c0 + cl + 1) * KK;
                    n0 = *(const float2*)(Wq0 + co);
                    n1 = *(const float2*)(Wq1 + co);
                    n2 = *(const float2*)(Wq2 + co);
                    n3 = *(const float2*)(Wq3 + co);
                }

                const float* arow = sA + cl * 320 + ml;   // arow[q] = a[c][m-63+q]
                QBLOCK2(w0, 0)
                QBLOCK2(w1, 1)
                QBLOCK2(w2, 2)
                QBLOCK2(w3, 3)

                w0 = n0; w1 = n1; w2 = n2; w3 = n3;
            }
        }
        __syncthreads();   // sA reads done + sFlag reset visible before next stage
    }

    if (m < MM) {
        float2* o = (float2*)(recon + (size_t)b * LL + 4 * m + rp);
        *o = make_float2(accA, accB);
    }
}

extern "C" void kernel_launch(void* const* d_in, const int* in_sizes, int n_in,
                              void* d_out, int out_size, void* d_ws, size_t ws_size,
                              hipStream_t stream) {
    const float* x = (const float*)d_in[0];   // [16][1][16000]
    const float* W = (const float*)d_in[1];   // [128][1][256]
    float* u = (float*)d_out;                 // u lives in d_out (fp32)

    float* ws    = (float*)d_ws;              // ~33.3 MB used
    float* drive = ws;                                    // 8062976
    float* recon = drive + (size_t)BB * CC * SS;          // 256000

    dim3 gConv(31, 16);   // ceil(3937/128) x B
    k_conv<0><<<gConv, 256, 0, stream>>>(x, W, drive, u);   // drive + u1

    for (int it = 0; it < 9; ++it) {   // iterations 2..10
        k_recon<<<dim3(16, 16), 512, 0, stream>>>(u, W, recon);
        if (it < 8)
            k_conv<1><<<gConv, 256, 0, stream>>>(recon, W, drive, u);
        else
            k_conv<2><<<gConv, 256, 0, stream>>>(recon, W, drive, u);  // final -> d_out
    }
}

// Round 11
// 1814.200 us; speedup vs baseline: 1.7631x; 1.0013x over previous
//
#include <hip/hip_runtime.h>
#include <math.h>

#define BB 16
#define CC 128
#define LL 16000
#define KK 256
#define SS 3937
#define MM 4000
#define THRS 0.5f
#define STEP 0.1f   // float32(0.01/0.1) == 0.1f

// ---------------------------------------------------------------------------
// Strided conv1d (K=256, stride=4), fp32 register-tiled implicit GEMM.
// R14 VERBATIM (proven ~60us). Single fmaf chain per output, k ascending.
// [bit-path frozen] tx=s (coalesced epilogue), ty=c, W natural rows in LDS
// stride 68, double-buffered. x window in LDS.
// MODE 0: init. MODE 1: LCA update. MODE 2: final -> hardshrink to d_out.
// ---------------------------------------------------------------------------
template<int MODE>
__global__ __launch_bounds__(256, 2) void k_conv(
    const float* __restrict__ in0,     // x (MODE 0) or recon (MODE 1/2)
    const float* __restrict__ W,       // [C][K] natural
    float* __restrict__ drive,
    float* __restrict__ u)
{
    __shared__ __align__(16) float sW[2][128 * 68];  // 2 x 34.8 KB
    __shared__ __align__(16) float sX[768];
    __shared__ int sFlag;

    const int tid = threadIdx.x;
    const int tx = tid & 15;          // s-minor
    const int ty = tid >> 4;          // c-minor
    const int s0 = blockIdx.x * 128;
    const int b  = blockIdx.y;

    const int sc = tid >> 1;
    const int sg = (tid & 1) * 8;
    const float4* W4 = (const float4*)W;

    if (tid == 0) sFlag = 0;
    __syncthreads();

    bool nz = false;
    #pragma unroll
    for (int h = 0; h < 3; ++h) {
        int t = tid + 256 * h;
        int l = 4 * s0 + t;
        float v = (l < LL) ? in0[b * LL + l] : 0.f;
        sX[t] = v;
        nz |= (v != 0.f);
    }
    if (MODE != 0) { if (nz) atomicOr(&sFlag, 1); }
    __syncthreads();

    float acc[8][8];
    #pragma unroll
    for (int i = 0; i < 8; ++i)
        #pragma unroll
        for (int j = 0; j < 8; ++j) acc[i][j] = 0.f;

    const bool doit = (MODE == 0) || (sFlag != 0);   // block-uniform

    if (doit) {
        {
            float4* dst = (float4*)sW[0];
            #pragma unroll
            for (int w = 0; w < 8; ++w)
                dst[sc * 17 + sg + w] = W4[sc * 64 + sg + w];
        }
        __syncthreads();

        for (int kc = 0; kc < 4; ++kc) {         // k chunks ascending
            float4 pre[8];
            if (kc < 3) {
                #pragma unroll
                for (int w = 0; w < 8; ++w)
                    pre[w] = W4[sc * 64 + (kc + 1) * 16 + sg + w];
            }

            const float* wbuf = sW[kc & 1];
            const int xoff = 64 * kc;

            for (int kk4 = 0; kk4 < 16; ++kk4) {          // k ascending
                float4 xq[8];
                #pragma unroll
                for (int j = 0; j < 8; ++j)
                    xq[j] = *(const float4*)&sX[4 * (tx + 16 * j) + xoff + 4 * kk4];
                float4 w4[8];
                #pragma unroll
                for (int i = 0; i < 8; ++i)
                    w4[i] = *(const float4*)&wbuf[(ty + 16 * i) * 68 + 4 * kk4];
                #pragma unroll
                for (int dk = 0; dk < 4; ++dk) {
                    #pragma unroll
                    for (int i = 0; i < 8; ++i) {
                        float wv = (&w4[i].x)[dk];
                        #pragma unroll
                        for (int j = 0; j < 8; ++j)
                            acc[i][j] = fmaf(wv, (&xq[j].x)[dk], acc[i][j]);
                    }
                }
            }

            if (kc < 3) {
                float4* dst = (float4*)sW[(kc + 1) & 1];
                #pragma unroll
                for (int w = 0; w < 8; ++w)
                    dst[sc * 17 + sg + w] = pre[w];
            }
            __syncthreads();
        }
    }

    // epilogue: locked fp32 elementwise chain; s-contiguous stores
    #pragma unroll
    for (int j = 0; j < 8; ++j) {
        int s = s0 + tx + 16 * j;
        if (s < SS) {
            #pragma unroll
            for (int i = 0; i < 8; ++i) {
                int c = ty + 16 * i;
                size_t idx = (size_t)(b * CC + c) * SS + s;
                if (MODE == 0) {
                    float d = acc[i][j];
                    drive[idx] = d;
                    u[idx] = __fmul_rn(STEP, d);   // u1 = 0 + 0.1f*drive
                } else {
                    float uo = u[idx];
                    float dr = drive[idx];
                    float a  = (fabsf(uo) > THRS) ? uo : 0.f;
                    float t1 = __fsub_rn(dr, uo);
                    float t2 = __fsub_rn(t1, acc[i][j]);
                    float t3 = __fadd_rn(t2, a);
                    float t4 = __fmul_rn(STEP, t3);
                    float un = __fadd_rn(uo, t4);
                    if (MODE == 1) u[idx] = un;
                    else           u[idx] = (fabsf(un) > THRS) ? un : 0.f;  // final
                }
            }
        }
    }
}

// ---------------------------------------------------------------------------
// Transpose-conv (recon). Chain [bit-path frozen] identical to R5-R27:
//   recon[b][4m+r]: for c = 0..127 asc (4 stages x 32), q = 0..63 asc:
//       acc_r = fmaf(a[b][c][m-63+q], W[c][4*(63-q)+r], acc_r)
// R28 = R27 (r-pair split + fmac_dpp, 129us) + PER-CHANNEL sparsity skip.
// Post-mortem R27: balanced VALU/LDS machine, ~2x micro-headroom left.
// The unexploited structure is LCA sparsity: a = hardshrink(u, 0.5) is
// sparse by design (early iters nearly empty; converged code sparse).
// Stage-level skip (all 32 ch zero) almost never fires once active.
//  - Staging builds a per-thread 32-bit mask of channels with any
//    nonzero in this block's 320-window; one atomicOr per thread
//    (issued only if mask nonzero).
//  - Compute iterates set bits only: cl = ctz(rem) (uniform SALU),
//    w-prefetch follows the next ACTIVE channel. Skipped channels
//    contribute exactly fma(0,w,acc)=acc -- same reasoning the proven
//    stage-level skip already relies on -> bit-safe.
//  - Worst case (mask full): few-us overhead vs R27.
// ---------------------------------------------------------------------------
#define FMAC_DPP(ACC, WREG, AREG, QI) \
    asm("v_fmac_f32_dpp %0, %1, %2 row_newbcast:" #QI " row_mask:0xf bank_mask:0xf" \
        : "+v"(ACC) : "v"(WREG), "v"(AREG))

#define QSTEP2(WQ, QB, QI) { \
    float a_ = arow[16 * (QB) + (QI)]; \
    FMAC_DPP(accA, WQ.x, a_, QI); \
    FMAC_DPP(accB, WQ.y, a_, QI); }

#define QBLOCK2(WQ, QB) \
    QSTEP2(WQ, QB, 0)  QSTEP2(WQ, QB, 1)  QSTEP2(WQ, QB, 2)  QSTEP2(WQ, QB, 3)  \
    QSTEP2(WQ, QB, 4)  QSTEP2(WQ, QB, 5)  QSTEP2(WQ, QB, 6)  QSTEP2(WQ, QB, 7)  \
    QSTEP2(WQ, QB, 8)  QSTEP2(WQ, QB, 9)  QSTEP2(WQ, QB, 10) QSTEP2(WQ, QB, 11) \
    QSTEP2(WQ, QB, 12) QSTEP2(WQ, QB, 13) QSTEP2(WQ, QB, 14) QSTEP2(WQ, QB, 15)

__global__ __launch_bounds__(512, 1) void k_recon(
    const float* __restrict__ u,
    const float* __restrict__ W,       // [C][K] natural layout
    float* __restrict__ recon)         // [B][LL]
{
    __shared__ __align__(16) float sA[32 * 320];   // 40.96 KB (stride 320)
    __shared__ int sMask;

    const int tid  = threadIdx.x;      // [0,512)
    const int p    = tid & 15;         // row position for w layout
    const int ml   = tid & 255;        // m_local
    const int rp   = (tid >> 8) << 1;  // 0 | 2, wave-uniform
    const int m0 = blockIdx.x * 256;
    const int b  = blockIdx.y;
    const int m  = m0 + ml;

    if (tid == 0) sMask = 0;
    __syncthreads();

    float accA = 0.f, accB = 0.f;      // r = rp, rp+1

    // per-lane w fetch bases: quarter qb, element 4*(63-16qb-p)+rp
    const float* Wq0 = W + 4 * (63 - p)      + rp;
    const float* Wq1 = W + 4 * (63 - 16 - p) + rp;
    const float* Wq2 = W + 4 * (63 - 32 - p) + rp;
    const float* Wq3 = W + 4 * (63 - 48 - p) + rp;

    for (int cs = 0; cs < 4; ++cs) {            // 32-channel stages, c ascending
        const int c0 = cs * 32;

        // ---- stage a-tile (hardshrink at write; per-channel nz mask) ----
        int tm = 0;
        #pragma unroll
        for (int h = 0; h < 20; ++h) {          // 20*512 = 32*320 elements
            int idx = tid + 512 * h;
            int cl  = idx / 320;
            int col = idx - cl * 320;
            int mm  = m0 - 63 + col;
            float v = 0.f;
            if (col < 319 && mm >= 0 && mm < SS) {
                float uu = u[(size_t)(b * CC + c0 + cl) * SS + mm];
                v = (fabsf(uu) > THRS) ? uu : 0.f;
            }
            sA[idx] = v;
            if (v != 0.f) tm |= (1 << cl);
        }
        if (tm) atomicOr(&sMask, tm);

        __syncthreads();                        // staging + mask complete
        const int mask = sMask;                 // block-uniform read
        __syncthreads();                        // all threads have read mask
        if (tid == 0) sMask = 0;                // reset (ordered by loop-end barrier)

        if (mask) {
            int rem = mask;
            int cl  = __builtin_ctz(rem);       // first active channel
            rem &= rem - 1;

            // w for first active channel
            size_t co = (size_t)(c0 + cl) * KK;
            float2 w0 = *(const float2*)(Wq0 + co);
            float2 w1 = *(const float2*)(Wq1 + co);
            float2 w2 = *(const float2*)(Wq2 + co);
            float2 w3 = *(const float2*)(Wq3 + co);

            while (true) {
                int ncl = -1;
                float2 n0, n1, n2, n3;
                if (rem) {                      // prefetch next ACTIVE channel
                    ncl = __builtin_ctz(rem);
                    size_t cn = (size_t)(c0 + ncl) * KK;
                    n0 = *(const float2*)(Wq0 + cn);
                    n1 = *(const float2*)(Wq1 + cn);
                    n2 = *(const float2*)(Wq2 + cn);
                    n3 = *(const float2*)(Wq3 + cn);
                }

                const float* arow = sA + cl * 320 + ml;   // arow[q] = a[c][m-63+q]
                QBLOCK2(w0, 0)
                QBLOCK2(w1, 1)
                QBLOCK2(w2, 2)
                QBLOCK2(w3, 3)

                if (ncl < 0) break;
                cl = ncl;
                rem &= rem - 1;
                w0 = n0; w1 = n1; w2 = n2; w3 = n3;
            }
        }
        __syncthreads();   // sA reads done + sMask reset visible before next stage
    }

    if (m < MM) {
        float2* o = (float2*)(recon + (size_t)b * LL + 4 * m + rp);
        *o = make_float2(accA, accB);
    }
}

extern "C" void kernel_launch(void* const* d_in, const int* in_sizes, int n_in,
                              void* d_out, int out_size, void* d_ws, size_t ws_size,
                              hipStream_t stream) {
    const float* x = (const float*)d_in[0];   // [16][1][16000]
    const float* W = (const float*)d_in[1];   // [128][1][256]
    float* u = (float*)d_out;                 // u lives in d_out (fp32)

    float* ws    = (float*)d_ws;              // ~33.3 MB used
    float* drive = ws;                                    // 8062976
    float* recon = drive + (size_t)BB * CC * SS;          // 256000

    dim3 gConv(31, 16);   // ceil(3937/128) x B
    k_conv<0><<<gConv, 256, 0, stream>>>(x, W, drive, u);   // drive + u1

    for (int it = 0; it < 9; ++it) {   // iterations 2..10
        k_recon<<<dim3(16, 16), 512, 0, stream>>>(u, W, recon);
        if (it < 8)
            k_conv<1><<<gConv, 256, 0, stream>>>(recon, W, drive, u);
        else
            k_conv<2><<<gConv, 256, 0, stream>>>(recon, W, drive, u);  // final -> d_out
    }
}

// Round 13
// 1699.929 us; speedup vs baseline: 1.8816x; 1.0672x over previous
//
#include <hip/hip_runtime.h>
#include <math.h>

#define BB 16
#define CC 128
#define LL 16000
#define KK 256
#define SS 3937
#define MM 4000
#define THRS 0.5f
#define STEP 0.1f   // float32(0.01/0.1) == 0.1f

// ---------------------------------------------------------------------------
// Strided conv1d (K=256, stride=4), fp32 register-tiled implicit GEMM.
// R14 VERBATIM (proven ~60us). Single fmaf chain per output, k ascending.
// MODE 0: init. MODE 1: LCA update. MODE 2: final -> hardshrink to d_out.
// ---------------------------------------------------------------------------
template<int MODE>
__global__ __launch_bounds__(256, 2) void k_conv(
    const float* __restrict__ in0,     // x (MODE 0) or recon (MODE 1/2)
    const float* __restrict__ W,       // [C][K] natural
    float* __restrict__ drive,
    float* __restrict__ u)
{
    __shared__ __align__(16) float sW[2][128 * 68];  // 2 x 34.8 KB
    __shared__ __align__(16) float sX[768];
    __shared__ int sFlag;

    const int tid = threadIdx.x;
    const int tx = tid & 15;          // s-minor
    const int ty = tid >> 4;          // c-minor
    const int s0 = blockIdx.x * 128;
    const int b  = blockIdx.y;

    const int sc = tid >> 1;
    const int sg = (tid & 1) * 8;
    const float4* W4 = (const float4*)W;

    if (tid == 0) sFlag = 0;
    __syncthreads();

    bool nz = false;
    #pragma unroll
    for (int h = 0; h < 3; ++h) {
        int t = tid + 256 * h;
        int l = 4 * s0 + t;
        float v = (l < LL) ? in0[b * LL + l] : 0.f;
        sX[t] = v;
        nz |= (v != 0.f);
    }
    if (MODE != 0) { if (nz) atomicOr(&sFlag, 1); }
    __syncthreads();

    float acc[8][8];
    #pragma unroll
    for (int i = 0; i < 8; ++i)
        #pragma unroll
        for (int j = 0; j < 8; ++j) acc[i][j] = 0.f;

    const bool doit = (MODE == 0) || (sFlag != 0);   // block-uniform

    if (doit) {
        {
            float4* dst = (float4*)sW[0];
            #pragma unroll
            for (int w = 0; w < 8; ++w)
                dst[sc * 17 + sg + w] = W4[sc * 64 + sg + w];
        }
        __syncthreads();

        for (int kc = 0; kc < 4; ++kc) {         // k chunks ascending
            float4 pre[8];
            if (kc < 3) {
                #pragma unroll
                for (int w = 0; w < 8; ++w)
                    pre[w] = W4[sc * 64 + (kc + 1) * 16 + sg + w];
            }

            const float* wbuf = sW[kc & 1];
            const int xoff = 64 * kc;

            for (int kk4 = 0; kk4 < 16; ++kk4) {          // k ascending
                float4 xq[8];
                #pragma unroll
                for (int j = 0; j < 8; ++j)
                    xq[j] = *(const float4*)&sX[4 * (tx + 16 * j) + xoff + 4 * kk4];
                float4 w4[8];
                #pragma unroll
                for (int i = 0; i < 8; ++i)
                    w4[i] = *(const float4*)&wbuf[(ty + 16 * i) * 68 + 4 * kk4];
                #pragma unroll
                for (int dk = 0; dk < 4; ++dk) {
                    #pragma unroll
                    for (int i = 0; i < 8; ++i) {
                        float wv = (&w4[i].x)[dk];
                        #pragma unroll
                        for (int j = 0; j < 8; ++j)
                            acc[i][j] = fmaf(wv, (&xq[j].x)[dk], acc[i][j]);
                    }
                }
            }

            if (kc < 3) {
                float4* dst = (float4*)sW[(kc + 1) & 1];
                #pragma unroll
                for (int w = 0; w < 8; ++w)
                    dst[sc * 17 + sg + w] = pre[w];
            }
            __syncthreads();
        }
    }

    // epilogue: locked fp32 elementwise chain; s-contiguous stores
    #pragma unroll
    for (int j = 0; j < 8; ++j) {
        int s = s0 + tx + 16 * j;
        if (s < SS) {
            #pragma unroll
            for (int i = 0; i < 8; ++i) {
                int c = ty + 16 * i;
                size_t idx = (size_t)(b * CC + c) * SS + s;
                if (MODE == 0) {
                    float d = acc[i][j];
                    drive[idx] = d;
                    u[idx] = __fmul_rn(STEP, d);   // u1 = 0 + 0.1f*drive
                } else {
                    float uo = u[idx];
                    float dr = drive[idx];
                    float a  = (fabsf(uo) > THRS) ? uo : 0.f;
                    float t1 = __fsub_rn(dr, uo);
                    float t2 = __fsub_rn(t1, acc[i][j]);
                    float t3 = __fadd_rn(t2, a);
                    float t4 = __fmul_rn(STEP, t3);
                    float un = __fadd_rn(uo, t4);
                    if (MODE == 1) u[idx] = un;
                    else           u[idx] = (fabsf(un) > THRS) ? un : 0.f;  // final
                }
            }
        }
    }
}

// ---------------------------------------------------------------------------
// Transpose-conv (recon). Chain [bit-path frozen — R29 PROVED it: q-half
// regroup flipped a hardshrink boundary, absmax 0.5] identical to R5-R28:
//   recon[b][4m+r]: for c = 0..127 asc (4 stages x 32), q = 0..63 asc:
//       acc_r = fmaf(a[b][c][m-63+q], W[c][4*(63-q)+r], acc_r)
// R30 = R27 VERBATIM compute (r-pair split + fmac_dpp, proven 129us,
// absmax 0.0039) + double-buffered async staging (T14):
//  - sA[2] (82KB); per iter: barrier -> read per-stage flag BIT ->
//    issue next stage's 20 global loads into regs -> compute current
//    (load latency hides under ~25us of fmac_dpp) -> hardshrink +
//    ds_write other buffer -> atomicOr bit cs+1.
//  - Flag = one word, bit cs per stage, never reset: iter cs reads only
//    bit cs while staging sets bit cs+1 -> no race, ONE barrier/iter.
//  - Staged values, compute order, fmac ops byte-identical to R27.
// ---------------------------------------------------------------------------
#define FMAC_DPP(ACC, WREG, AREG, QI) \
    asm("v_fmac_f32_dpp %0, %1, %2 row_newbcast:" #QI " row_mask:0xf bank_mask:0xf" \
        : "+v"(ACC) : "v"(WREG), "v"(AREG))

#define QSTEP2(WQ, QB, QI) { \
    float a_ = arow[16 * (QB) + (QI)]; \
    FMAC_DPP(accA, WQ.x, a_, QI); \
    FMAC_DPP(accB, WQ.y, a_, QI); }

#define QBLOCK2(WQ, QB) \
    QSTEP2(WQ, QB, 0)  QSTEP2(WQ, QB, 1)  QSTEP2(WQ, QB, 2)  QSTEP2(WQ, QB, 3)  \
    QSTEP2(WQ, QB, 4)  QSTEP2(WQ, QB, 5)  QSTEP2(WQ, QB, 6)  QSTEP2(WQ, QB, 7)  \
    QSTEP2(WQ, QB, 8)  QSTEP2(WQ, QB, 9)  QSTEP2(WQ, QB, 10) QSTEP2(WQ, QB, 11) \
    QSTEP2(WQ, QB, 12) QSTEP2(WQ, QB, 13) QSTEP2(WQ, QB, 14) QSTEP2(WQ, QB, 15)

__global__ __launch_bounds__(512, 1) void k_recon(
    const float* __restrict__ u,
    const float* __restrict__ W,       // [C][K] natural layout
    float* __restrict__ recon)         // [B][LL]
{
    __shared__ __align__(16) float sA[2][32 * 320];   // 2 x 40.96 KB
    __shared__ int sFlag;

    const int tid  = threadIdx.x;      // [0,512)
    const int p    = tid & 15;         // row position for w layout
    const int ml   = tid & 255;        // m_local
    const int rp   = (tid >> 8) << 1;  // 0 | 2, wave-uniform
    const int m0 = blockIdx.x * 256;
    const int b  = blockIdx.y;
    const int m  = m0 + ml;

    if (tid == 0) sFlag = 0;
    __syncthreads();

    float accA = 0.f, accB = 0.f;      // r = rp, rp+1

    // per-lane w fetch bases: quarter qb, element 4*(63-16qb-p)+rp
    const float* Wq0 = W + 4 * (63 - p)      + rp;
    const float* Wq1 = W + 4 * (63 - 16 - p) + rp;
    const float* Wq2 = W + 4 * (63 - 32 - p) + rp;
    const float* Wq3 = W + 4 * (63 - 48 - p) + rp;

    // ---- prologue: stage 0 into buf 0 (serial) ----
    {
        bool nz = false;
        #pragma unroll
        for (int h = 0; h < 20; ++h) {          // 20*512 = 32*320 elements
            int idx = tid + 512 * h;
            int cl  = idx / 320;
            int col = idx - cl * 320;
            int mm  = m0 - 63 + col;
            float v = 0.f;
            if (col < 319 && mm >= 0 && mm < SS) {
                float uu = u[(size_t)(b * CC + cl) * SS + mm];
                v = (fabsf(uu) > THRS) ? uu : 0.f;
            }
            sA[0][idx] = v;
            nz |= (v != 0.f);
        }
        if (nz) atomicOr(&sFlag, 1);            // bit 0
    }

    for (int cs = 0; cs < 4; ++cs) {            // 32-channel stages, c ascending
        const int c0 = cs * 32;

        __syncthreads();                        // buf[cs&1] staged, bit cs set
        const int f = (sFlag >> cs) & 1;        // others only touch bit cs+1

        // ---- issue next stage's global loads into regs (latency hides
        //      under compute below) ----
        float pv[20];
        if (cs < 3) {
            const int c0n = (cs + 1) * 32;
            #pragma unroll
            for (int h = 0; h < 20; ++h) {
                int idx = tid + 512 * h;
                int cl  = idx / 320;
                int col = idx - cl * 320;
                int mm  = m0 - 63 + col;
                float v = 0.f;
                if (col < 319 && mm >= 0 && mm < SS)
                    v = u[(size_t)(b * CC + c0n + cl) * SS + mm];
                pv[h] = v;
            }
        }

        // ---- compute on buf[cs&1] (R27 verbatim) ----
        if (f) {
            const float* buf = sA[cs & 1];
            // prologue: w quarters for cl=0
            size_t co = (size_t)c0 * KK;
            float2 w0 = *(const float2*)(Wq0 + co);
            float2 w1 = *(const float2*)(Wq1 + co);
            float2 w2 = *(const float2*)(Wq2 + co);
            float2 w3 = *(const float2*)(Wq3 + co);

            for (int cl = 0; cl < 32; ++cl) {   // c ascending
                float2 n0, n1, n2, n3;
                if (cl < 31) {                  // prefetch next channel
                    size_t cn = (size_t)(c0 + cl + 1) * KK;
                    n0 = *(const float2*)(Wq0 + cn);
                    n1 = *(const float2*)(Wq1 + cn);
                    n2 = *(const float2*)(Wq2 + cn);
                    n3 = *(const float2*)(Wq3 + cn);
                }

                const float* arow = buf + cl * 320 + ml;  // arow[q] = a[c][m-63+q]
                QBLOCK2(w0, 0)
                QBLOCK2(w1, 1)
                QBLOCK2(w2, 2)
                QBLOCK2(w3, 3)

                w0 = n0; w1 = n1; w2 = n2; w3 = n3;
            }
        }

        // ---- finish staging stage cs+1 into buf[(cs+1)&1] ----
        if (cs < 3) {
            bool nz = false;
            float* dst = sA[(cs + 1) & 1];
            #pragma unroll
            for (int h = 0; h < 20; ++h) {
                int idx = tid + 512 * h;
                float uu = pv[h];
                float v = (fabsf(uu) > THRS) ? uu : 0.f;
                dst[idx] = v;
                nz |= (v != 0.f);
            }
            if (nz) atomicOr(&sFlag, 1 << (cs + 1));
        }
    }

    if (m < MM) {
        float2* o = (float2*)(recon + (size_t)b * LL + 4 * m + rp);
        *o = make_float2(accA, accB);
    }
}

extern "C" void kernel_launch(void* const* d_in, const int* in_sizes, int n_in,
                              void* d_out, int out_size, void* d_ws, size_t ws_size,
                              hipStream_t stream) {
    const float* x = (const float*)d_in[0];   // [16][1][16000]
    const float* W = (const float*)d_in[1];   // [128][1][256]
    float* u = (float*)d_out;                 // u lives in d_out (fp32)

    float* ws    = (float*)d_ws;              // ~33.3 MB used
    float* drive = ws;                                    // 8062976
    float* recon = drive + (size_t)BB * CC * SS;          // 256000

    dim3 gConv(31, 16);   // ceil(3937/128) x B
    k_conv<0><<<gConv, 256, 0, stream>>>(x, W, drive, u);   // drive + u1

    for (int it = 0; it < 9; ++it) {   // iterations 2..10
        k_recon<<<dim3(16, 16), 512, 0, stream>>>(u, W, recon);
        if (it < 8)
            k_conv<1><<<gConv, 256, 0, stream>>>(recon, W, drive, u);
        else
            k_conv<2><<<gConv, 256, 0, stream>>>(recon, W, drive, u);  // final -> d_out
    }
}